// Round 1
// baseline (141.840 us; speedup 1.0000x reference)
//
#include <hip/hip_runtime.h>
#include <hip/hip_bf16.h>

#define UNITS 128
#define NHEADS 8
#define DHEAD 16
#define SEQ 4096
#define BATCH 2
#define KVBLK 64
#define QTILE 16
#define NWAVES 4
#define LOG2E 1.44269504f

typedef __bf16 bf8 __attribute__((ext_vector_type(8)));
typedef __bf16 bf4 __attribute__((ext_vector_type(4)));
typedef __bf16 bf2 __attribute__((ext_vector_type(2)));
typedef float f4 __attribute__((ext_vector_type(4)));

// LDS pitches: odd multiples of 16B so ds_read_b128 is aligned and row-stride
// bank aliasing is 2-way (free, m136). Klds pitch 56 el = 112B; Vt/P pitch 72 el = 144B.
#define KP 56
#define VP 72

__global__ __launch_bounds__(256, 4) void attn_fwd(
    const float* __restrict__ memory, const float* __restrict__ query,
    const int* __restrict__ seq_mask, float* __restrict__ out)
{
    const int bidx = blockIdx.z;   // batch
    const int h    = blockIdx.y;   // head
    const int qblk = blockIdx.x;   // block of 64 query rows
    const int tid  = threadIdx.x;
    const int wave = tid >> 6;
    const int lane = tid & 63;
    const int col  = lane & 15;    // q index (B-frag col) / d index (PV A row)
    const int g    = lane >> 4;    // 16-lane group

    __shared__ __bf16 Klds[KVBLK][KP];            // [key][d], d 16..31 zero pad
    __shared__ __bf16 Vt[DHEAD][VP];              // [d][key]
    __shared__ __bf16 Plds[NWAVES][QTILE][VP];    // per-wave P^T as [q][key]
    __shared__ float  maskadd[KVBLK];

    // zero the K pad region (d in [16,32)) once; never rewritten
    for (int i = tid; i < KVBLK * 16; i += 256)
        Klds[i >> 4][16 + (i & 15)] = (__bf16)0.f;

    // Q fragment (held in registers for the whole kernel), scaled by d^-0.5
    const int qrow = qblk * (QTILE * NWAVES) + wave * QTILE + col;
    bf8 qfrag;
    if (g < 2) {
        const float* qp = query + ((size_t)bidx * SEQ + qrow) * UNITS + h * DHEAD + g * 8;
        #pragma unroll
        for (int j = 0; j < 8; ++j) qfrag[j] = (__bf16)(qp[j] * 0.25f);
    } else {
        #pragma unroll
        for (int j = 0; j < 8; ++j) qfrag[j] = (__bf16)0.f;
    }

    float m = -1e30f, l = 0.f;
    f4 acc = {0.f, 0.f, 0.f, 0.f};

    const float* kbase = memory + (size_t)bidx * SEQ * (2 * UNITS) + h * DHEAD;
    const float* vbase = kbase + UNITS;

    for (int blk = 0; blk < SEQ / KVBLK; ++blk) {
        const int k0 = blk * KVBLK;
        __syncthreads();   // prior compute done before restaging
        {
            // stage K (row-major, bf16) and V^T; 256 threads: key=tid>>2, 4 d's each
            const int key = tid >> 2;
            const int d0  = (tid & 3) * 4;
            const float4 kv = *(const float4*)(kbase + (size_t)(k0 + key) * (2 * UNITS) + d0);
            const float4 vv = *(const float4*)(vbase + (size_t)(k0 + key) * (2 * UNITS) + d0);
            bf4 ks;
            ks[0] = (__bf16)kv.x; ks[1] = (__bf16)kv.y;
            ks[2] = (__bf16)kv.z; ks[3] = (__bf16)kv.w;
            *(bf4*)&Klds[key][d0] = ks;
            Vt[d0 + 0][key] = (__bf16)vv.x;
            Vt[d0 + 1][key] = (__bf16)vv.y;
            Vt[d0 + 2][key] = (__bf16)vv.z;
            Vt[d0 + 3][key] = (__bf16)vv.w;
            if (tid < KVBLK)
                maskadd[tid] = seq_mask[(size_t)bidx * SEQ + k0 + tid] ? 0.f : -1e30f;
        }
        __syncthreads();

        // ---- S^T tile: mfma(A=K, B=Q) -> D[key][q], col=q, row=g*4+reg=key%16
        float sv[16];
        #pragma unroll
        for (int t = 0; t < 4; ++t) {
            bf8 kfrag = *(const bf8*)&Klds[t * 16 + col][g * 8];
            f4 z = {0.f, 0.f, 0.f, 0.f};
            f4 s = __builtin_amdgcn_mfma_f32_16x16x32_bf16(kfrag, qfrag, z, 0, 0, 0);
            const float4 ma = *(const float4*)&maskadd[t * 16 + g * 4];
            sv[t * 4 + 0] = s[0] + ma.x;
            sv[t * 4 + 1] = s[1] + ma.y;
            sv[t * 4 + 2] = s[2] + ma.z;
            sv[t * 4 + 3] = s[3] + ma.w;
        }

        // ---- online softmax: 16 in-lane + 2 shfl_xor (keys for query `col`
        //      live in lanes {col, col+16, col+32, col+48})
        float bmax = sv[0];
        #pragma unroll
        for (int j = 1; j < 16; ++j) bmax = fmaxf(bmax, sv[j]);
        bmax = fmaxf(bmax, __shfl_xor(bmax, 16));
        bmax = fmaxf(bmax, __shfl_xor(bmax, 32));
        const float m_new = fmaxf(m, bmax);
        const float scale_old = exp2f((m - m_new) * LOG2E);
        float bsum = 0.f;
        #pragma unroll
        for (int j = 0; j < 16; ++j) {
            sv[j] = exp2f((sv[j] - m_new) * LOG2E);
            bsum += sv[j];
        }
        bsum += __shfl_xor(bsum, 16);
        bsum += __shfl_xor(bsum, 32);
        l = l * scale_old + bsum;
        m = m_new;
        #pragma unroll
        for (int r = 0; r < 4; ++r) acc[r] *= scale_old;

        // ---- write P^T (bf16) to per-wave LDS: lane holds (q=col, key=t*16+g*4+r)
        #pragma unroll
        for (int t = 0; t < 4; ++t) {
            #pragma unroll
            for (int rp = 0; rp < 2; ++rp) {
                bf2 pk;
                pk[0] = (__bf16)sv[t * 4 + rp * 2 + 0];
                pk[1] = (__bf16)sv[t * 4 + rp * 2 + 1];
                *(bf2*)&Plds[wave][col][t * 16 + g * 4 + rp * 2] = pk;
            }
        }

        // ---- PV: out^T = V^T x P^T (contraction over 64 keys = 2 mfma)
        #pragma unroll
        for (int half = 0; half < 2; ++half) {
            bf8 vfrag = *(const bf8*)&Vt[col][half * 32 + g * 8];
            bf8 pfrag = *(const bf8*)&Plds[wave][col][half * 32 + g * 8];
            acc = __builtin_amdgcn_mfma_f32_16x16x32_bf16(vfrag, pfrag, acc, 0, 0, 0);
        }
    }

    // ---- epilogue: out[qrow][h*16 + g*4 + reg] = acc[reg] / l
    const float invl = 1.0f / l;
    float4 o;
    o.x = acc[0] * invl; o.y = acc[1] * invl;
    o.z = acc[2] * invl; o.w = acc[3] * invl;
    *(float4*)(out + ((size_t)bidx * SEQ + qrow) * UNITS + h * DHEAD + g * 4) = o;
}

extern "C" void kernel_launch(void* const* d_in, const int* in_sizes, int n_in,
                              void* d_out, int out_size, void* d_ws, size_t ws_size,
                              hipStream_t stream) {
    const float* memory   = (const float*)d_in[0];
    const float* query    = (const float*)d_in[1];
    const int*   seq_mask = (const int*)d_in[2];
    float*       out      = (float*)d_out;
    dim3 grid(SEQ / (QTILE * NWAVES), NHEADS, BATCH);
    attn_fwd<<<grid, 256, 0, stream>>>(memory, query, seq_mask, out);
}

// Round 2
// 122.854 us; speedup vs baseline: 1.1545x; 1.1545x over previous
//
#include <hip/hip_runtime.h>
#include <hip/hip_bf16.h>

#define UNITS 128
#define NHEADS 8
#define DHEAD 16
#define SEQ 4096
#define BATCH 2
#define KVBLK 64
#define NBLK (SEQ / KVBLK)
#define QTILE 16
#define NWAVES 4

typedef __bf16 bf8 __attribute__((ext_vector_type(8)));
typedef __bf16 bf4 __attribute__((ext_vector_type(4)));
typedef __bf16 bf2 __attribute__((ext_vector_type(2)));
typedef float f4 __attribute__((ext_vector_type(4)));

// LDS pitches: odd multiples of 16B -> aligned ds_read_b128, low row-aliasing.
#define KP 56
#define VP 72

// Q pre-scale: d^-0.5 * log2(e) -> logits arrive in log2 domain (softmax uses exp2 directly)
#define QSCALE 0.3606737602f

__global__ __launch_bounds__(256, 4) void attn_fwd(
    const float* __restrict__ memory, const float* __restrict__ query,
    const int* __restrict__ seq_mask, float* __restrict__ out)
{
    const int bidx = blockIdx.z;
    const int h    = blockIdx.y;
    const int qblk = blockIdx.x;
    const int tid  = threadIdx.x;
    const int wave = tid >> 6;
    const int lane = tid & 63;
    const int col  = lane & 15;    // q index (QK B-frag) / d index (PV A-frag)
    const int g    = lane >> 4;

    __shared__ __bf16 Klds[2][KVBLK][KP];          // [buf][key][d], d 16..31 zero pad
    __shared__ __bf16 Vt[2][DHEAD][VP];            // [buf][d][key]
    __shared__ __bf16 Plds[NWAVES][QTILE][VP];     // per-wave P^T [q][key]
    __shared__ float  maskadd[2][KVBLK];

    // zero the K pad region (d in [16,32)) for both buffers, once
    for (int i = tid; i < 2 * KVBLK * 16; i += 256)
        Klds[i >> 10][(i >> 4) & 63][16 + (i & 15)] = (__bf16)0.f;

    // ---- Q fragment in registers (log2-domain scale folded in)
    const int qrow = qblk * (QTILE * NWAVES) + wave * QTILE + col;
    bf8 qfrag;
    if (g < 2) {
        const float* qp = query + ((size_t)bidx * SEQ + qrow) * UNITS + h * DHEAD + g * 8;
        #pragma unroll
        for (int j = 0; j < 8; ++j) qfrag[j] = (__bf16)(qp[j] * QSCALE);
    } else {
        #pragma unroll
        for (int j = 0; j < 8; ++j) qfrag[j] = (__bf16)0.f;
    }

    // ---- staging thread assignments
    const int skey = tid >> 2;            // K: one key, 4 d's
    const int sd   = (tid & 3) * 4;
    const int vkp  = (tid & 31) * 2;      // V: two consecutive keys, 2 d's
    const int vd   = (tid >> 5) * 2;

    const float* kptr = memory + (size_t)bidx * SEQ * (2 * UNITS)
                        + (size_t)skey * (2 * UNITS) + h * DHEAD + sd;
    const float* vptr = memory + (size_t)bidx * SEQ * (2 * UNITS)
                        + (size_t)vkp * (2 * UNITS) + h * DHEAD + UNITS + vd;
    const int* mptr = seq_mask + (size_t)bidx * SEQ + (tid & 63);

    // ---- prologue: load block 0 into registers
    float4 kreg = *(const float4*)kptr;
    float2 va   = *(const float2*)vptr;
    float2 vb   = *(const float2*)(vptr + 2 * UNITS);
    int   mreg  = (tid < KVBLK) ? *mptr : 0;

    float m = -1e30f, l = 0.f;
    f4 acc = {0.f, 0.f, 0.f, 0.f};

    for (int blk = 0; blk < NBLK; ++blk) {
        const int buf = blk & 1;

        // ---- write staged regs -> LDS buf (all 4B+ aligned, no shared dwords)
        bf4 ks;
        ks[0] = (__bf16)kreg.x; ks[1] = (__bf16)kreg.y;
        ks[2] = (__bf16)kreg.z; ks[3] = (__bf16)kreg.w;
        *(bf4*)&Klds[buf][skey][sd] = ks;
        bf2 v0; v0[0] = (__bf16)va.x; v0[1] = (__bf16)vb.x;
        bf2 v1; v1[0] = (__bf16)va.y; v1[1] = (__bf16)vb.y;
        *(bf2*)&Vt[buf][vd][vkp]     = v0;
        *(bf2*)&Vt[buf][vd + 1][vkp] = v1;
        if (tid < KVBLK) maskadd[buf][tid] = mreg ? 0.f : -1e30f;

        __syncthreads();   // the ONLY barrier: buf visible to all waves; vmcnt already drained

        // ---- issue next block's global loads; land during compute below
        if (blk + 1 < NBLK) {
            kptr += KVBLK * 2 * UNITS;
            vptr += KVBLK * 2 * UNITS;
            mptr += KVBLK;
            kreg = *(const float4*)kptr;
            va   = *(const float2*)vptr;
            vb   = *(const float2*)(vptr + 2 * UNITS);
            if (tid < KVBLK) mreg = *mptr;
        }

        // ---- S^T tile: mfma(A=K, B=Q) -> D[key][q]; col=q, key=t*16+g*4+reg
        float sv[16];
        #pragma unroll
        for (int t = 0; t < 4; ++t) {
            bf8 kfrag = *(const bf8*)&Klds[buf][t * 16 + col][g * 8];
            f4 z = {0.f, 0.f, 0.f, 0.f};
            f4 s = __builtin_amdgcn_mfma_f32_16x16x32_bf16(kfrag, qfrag, z, 0, 0, 0);
            const float4 ma = *(const float4*)&maskadd[buf][t * 16 + g * 4];
            sv[t * 4 + 0] = s[0] + ma.x;
            sv[t * 4 + 1] = s[1] + ma.y;
            sv[t * 4 + 2] = s[2] + ma.z;
            sv[t * 4 + 3] = s[3] + ma.w;
        }

        // ---- block max: tree reduce 16 in-lane, then 2 shfl_xor
        float mx[8];
        #pragma unroll
        for (int j = 0; j < 8; ++j) mx[j] = fmaxf(sv[j], sv[j + 8]);
        #pragma unroll
        for (int j = 0; j < 4; ++j) mx[j] = fmaxf(mx[j], mx[j + 4]);
        float bmax = fmaxf(fmaxf(mx[0], mx[1]), fmaxf(mx[2], mx[3]));
        bmax = fmaxf(bmax, __shfl_xor(bmax, 16));
        bmax = fmaxf(bmax, __shfl_xor(bmax, 32));

        // ---- online softmax (log2 domain), T13 defer-max: skip rescale if small growth
        const bool skip = __all(bmax <= m + 11.0f);
        if (!skip) {
            const float m_new = fmaxf(m, bmax);
            const float sc = exp2f(m - m_new);
            l *= sc;
            #pragma unroll
            for (int r = 0; r < 4; ++r) acc[r] *= sc;
            m = m_new;
        }
        float bsum0 = 0.f, bsum1 = 0.f;
        #pragma unroll
        for (int j = 0; j < 16; j += 2) {
            sv[j]     = exp2f(sv[j] - m);
            sv[j + 1] = exp2f(sv[j + 1] - m);
            bsum0 += sv[j];
            bsum1 += sv[j + 1];
        }
        float bsum = bsum0 + bsum1;
        bsum += __shfl_xor(bsum, 16);
        bsum += __shfl_xor(bsum, 32);
        l += bsum;

        // ---- P^T (bf16) to per-wave LDS
        #pragma unroll
        for (int t = 0; t < 4; ++t) {
            #pragma unroll
            for (int rp = 0; rp < 2; ++rp) {
                bf2 pk;
                pk[0] = (__bf16)sv[t * 4 + rp * 2 + 0];
                pk[1] = (__bf16)sv[t * 4 + rp * 2 + 1];
                *(bf2*)&Plds[wave][col][t * 16 + g * 4 + rp * 2] = pk;
            }
        }

        // ---- PV: out^T = V^T x P^T
        #pragma unroll
        for (int half = 0; half < 2; ++half) {
            bf8 vfrag = *(const bf8*)&Vt[buf][col][half * 32 + g * 8];
            bf8 pfrag = *(const bf8*)&Plds[wave][col][half * 32 + g * 8];
            acc = __builtin_amdgcn_mfma_f32_16x16x32_bf16(vfrag, pfrag, acc, 0, 0, 0);
        }
    }

    // ---- epilogue
    const float invl = 1.0f / l;
    float4 o;
    o.x = acc[0] * invl; o.y = acc[1] * invl;
    o.z = acc[2] * invl; o.w = acc[3] * invl;
    *(float4*)(out + ((size_t)bidx * SEQ + qrow) * UNITS + h * DHEAD + g * 4) = o;
}

extern "C" void kernel_launch(void* const* d_in, const int* in_sizes, int n_in,
                              void* d_out, int out_size, void* d_ws, size_t ws_size,
                              hipStream_t stream) {
    const float* memory   = (const float*)d_in[0];
    const float* query    = (const float*)d_in[1];
    const int*   seq_mask = (const int*)d_in[2];
    float*       out      = (float*)d_out;
    dim3 grid(SEQ / (QTILE * NWAVES), NHEADS, BATCH);
    attn_fwd<<<grid, 256, 0, stream>>>(memory, query, seq_mask, out);
}